// Round 1
// baseline (1669.172 us; speedup 1.0000x reference)
//
#include <hip/hip_runtime.h>
#include <math.h>

#define DIM 768
#define NTOK 1024
#define BATCH 4
#define HEADS 12
#define TOKENS (BATCH * NTOK)

// ---------------- router: logits + softmax (double accumulation) ----------------
__global__ void router_kernel(const float* __restrict__ x,
                              const float* __restrict__ rw,
                              const float* __restrict__ rb,
                              float* __restrict__ probs) {
    int t = blockIdx.x;           // token 0..4095
    int tid = threadIdx.x;        // 256 threads
    const float* xr = x + (size_t)t * DIM;
    double acc[4] = {0, 0, 0, 0};
    for (int k = tid; k < DIM; k += 256) {
        double xv = (double)xr[k];
        acc[0] += xv * (double)rw[k * 4 + 0];
        acc[1] += xv * (double)rw[k * 4 + 1];
        acc[2] += xv * (double)rw[k * 4 + 2];
        acc[3] += xv * (double)rw[k * 4 + 3];
    }
    __shared__ double red[256];
    __shared__ double logits[4];
    for (int e = 0; e < 4; ++e) {
        red[tid] = acc[e];
        __syncthreads();
        for (int s = 128; s > 0; s >>= 1) {
            if (tid < s) red[tid] += red[tid + s];
            __syncthreads();
        }
        if (tid == 0) logits[e] = red[0] + (double)rb[e];
        __syncthreads();
    }
    if (tid == 0) {
        double m = logits[0];
        for (int e = 1; e < 4; ++e) m = fmax(m, logits[e]);
        double s = 0.0, p[4];
        for (int e = 0; e < 4; ++e) { p[e] = exp(logits[e] - m); s += p[e]; }
        for (int e = 0; e < 4; ++e) probs[(size_t)t * 4 + e] = (float)(p[e] / s);
    }
}

// ---------------- greedy capacity routing: bitonic sort per expert ----------------
__global__ __launch_bounds__(1024) void route_kernel(const float* __restrict__ probs,
                                                     int* __restrict__ assigned_g,
                                                     int* __restrict__ dtok_g,
                                                     float* __restrict__ rprobs_g) {
    int b = blockIdx.x;
    int tid = threadIdx.x;  // 0..1023
    __shared__ float sp[1024];
    __shared__ int si[1024];
    __shared__ int s_av[1024];
    __shared__ int s_as[1024];
    s_av[tid] = 1;
    s_as[tid] = 0;
    const int ks_e[4] = {409, 307, 204, 104};
    const float* pb = probs + (size_t)b * NTOK * 4;
    for (int e = 3; e >= 1; --e) {
        __syncthreads();
        sp[tid] = s_av[tid] ? pb[tid * 4 + e] : -INFINITY;
        si[tid] = tid;
        // bitonic sort descending by (prob desc, idx asc) — matches lax.top_k ties
        for (int size = 2; size <= 1024; size <<= 1) {
            for (int stride = size >> 1; stride > 0; stride >>= 1) {
                __syncthreads();
                int i = tid, j = i ^ stride;
                if (j > i) {
                    float pi = sp[i], pj = sp[j];
                    int ii = si[i], ij = si[j];
                    bool up = ((i & size) == 0);
                    bool before = (pi > pj) || (pi == pj && ii < ij);
                    if (up != before) { sp[i] = pj; sp[j] = pi; si[i] = ij; si[j] = ii; }
                }
            }
        }
        __syncthreads();
        if (tid < ks_e[e]) {
            int tok = si[tid];
            s_as[tok] = e;
            s_av[tok] = 0;
        }
    }
    __syncthreads();
    int a = s_as[tid];
    assigned_g[b * NTOK + tid] = a;
    dtok_g[b * NTOK + tid] = DIM >> (3 - a);
    rprobs_g[b * NTOK + tid] = pb[tid * 4 + a];
}

// ---------------- layernorm (+ optional feature mask) ----------------
__global__ void ln_mask_kernel(const float* __restrict__ x,
                               const float* __restrict__ g,
                               const float* __restrict__ bta,
                               const int* __restrict__ dtok,  // null -> no mask
                               float* __restrict__ out) {
    int t = blockIdx.x;
    int tid = threadIdx.x;
    const float* xr = x + (size_t)t * DIM;
    float s = 0.0f;
    for (int k = tid; k < DIM; k += 256) s += xr[k];
    __shared__ float red[256];
    red[tid] = s;
    __syncthreads();
    for (int st = 128; st > 0; st >>= 1) {
        if (tid < st) red[tid] += red[tid + st];
        __syncthreads();
    }
    float mu = red[0] / DIM;
    __syncthreads();
    float v = 0.0f;
    for (int k = tid; k < DIM; k += 256) { float d = xr[k] - mu; v += d * d; }
    red[tid] = v;
    __syncthreads();
    for (int st = 128; st > 0; st >>= 1) {
        if (tid < st) red[tid] += red[tid + st];
        __syncthreads();
    }
    float rs = rsqrtf(red[0] / DIM + 1e-5f);
    int d = dtok ? dtok[t] : DIM;
    for (int k = tid; k < DIM; k += 256) {
        float val = (xr[k] - mu) * rs * g[k] + bta[k];
        out[(size_t)t * DIM + k] = (k < d) ? val : 0.0f;
    }
}

// ---------------- tiled fp32 GEMM with fused epilogues ----------------
// MODE 0: QKV — +bias, mask (col%768 < d_tok[row])
// MODE 1: WO  — +bias, mask (col < d_tok[row]), + residual aux(=x)
// MODE 2: FFN1 — +bias, exact GELU
// MODE 3: FFN2 — +bias, out = aux(=z) + rp[row]*c
template <int MODE>
__global__ __launch_bounds__(256) void gemm_kernel(const float* __restrict__ A,
                                                   const float* __restrict__ B,
                                                   const float* __restrict__ bias,
                                                   float* __restrict__ C,
                                                   int M, int NN, int K,
                                                   const int* __restrict__ dtok,
                                                   const float* __restrict__ aux,
                                                   const float* __restrict__ rp) {
    __shared__ float As[16][68];  // [k][m], pad 68 to spread write banks
    __shared__ float Bs[16][64];  // [k][n]
    int n0 = blockIdx.x * 64;
    int m0 = blockIdx.y * 64;
    int tid = threadIdx.x;
    int tx = tid & 15, ty = tid >> 4;
    float acc[4][4] = {};
    int ac = tid & 15, ar0 = tid >> 4;  // A load indices
    int bc = tid & 63, br0 = tid >> 6;  // B load indices
    for (int k0 = 0; k0 < K; k0 += 16) {
#pragma unroll
        for (int p = 0; p < 4; ++p) {
            int r = ar0 + p * 16;
            As[ac][r] = A[(size_t)(m0 + r) * K + k0 + ac];
        }
#pragma unroll
        for (int p = 0; p < 4; ++p) {
            int r = br0 + p * 4;
            Bs[r][bc] = B[(size_t)(k0 + r) * NN + n0 + bc];
        }
        __syncthreads();
#pragma unroll
        for (int kk = 0; kk < 16; ++kk) {
            float4 a4 = *(const float4*)&As[kk][ty * 4];
            float4 b4 = *(const float4*)&Bs[kk][tx * 4];
            float av[4] = {a4.x, a4.y, a4.z, a4.w};
            float bv[4] = {b4.x, b4.y, b4.z, b4.w};
#pragma unroll
            for (int i = 0; i < 4; ++i)
#pragma unroll
                for (int j = 0; j < 4; ++j) acc[i][j] = fmaf(av[i], bv[j], acc[i][j]);
        }
        __syncthreads();
    }
#pragma unroll
    for (int i = 0; i < 4; ++i) {
        int row = m0 + ty * 4 + i;
        int jbase = n0 + tx * 4;
        float4 o;
        float* op = (float*)&o;
#pragma unroll
        for (int j = 0; j < 4; ++j) {
            int col = jbase + j;
            float c = acc[i][j] + bias[col];
            if (MODE == 0) {
                int jm = col % 768;
                c = (jm < dtok[row]) ? c : 0.0f;
            } else if (MODE == 1) {
                c = (col < dtok[row]) ? c : 0.0f;
                c += aux[(size_t)row * NN + col];
            } else if (MODE == 2) {
                c = 0.5f * c * (1.0f + erff(c * 0.70710678118654752f));
            } else if (MODE == 3) {
                c = aux[(size_t)row * NN + col] + rp[row] * c;
            }
            op[j] = c;
        }
        *(float4*)&C[(size_t)row * NN + jbase] = o;
    }
}

// ---------------- attention: Q-tile=8, full scores in LDS, two-pass softmax ----------------
#define AQ 8
__global__ __launch_bounds__(256) void attn_kernel(const float* __restrict__ qkv,
                                                   const int* __restrict__ dtok,
                                                   float* __restrict__ attnout) {
    int qt = blockIdx.x;  // 0..127
    int h = blockIdx.y;   // 0..11
    int b = blockIdx.z;   // 0..3
    int tid = threadIdx.x;
    __shared__ float sq[AQ][68];
    __shared__ float kt[64][68];
    __shared__ float sc[AQ][1024];
    __shared__ float rmax[AQ], rsum[AQ], redm[AQ][32];
    int n0 = qt * AQ;
    size_t base = (size_t)b * NTOK * 2304;
    for (int idx = tid; idx < AQ * 64; idx += 256) {
        int qi = idx >> 6, d = idx & 63;
        sq[qi][d] = qkv[base + (size_t)(n0 + qi) * 2304 + h * 64 + d];
    }
    int q = tid >> 5;  // 0..7
    int l = tid & 31;  // 0..31
    // phase 1: scores = q.k * 1/8
    for (int t0 = 0; t0 < 16; ++t0) {
        __syncthreads();
        for (int idx = tid; idx < 64 * 64; idx += 256) {
            int kk = idx >> 6, d = idx & 63;
            kt[kk][d] = qkv[base + (size_t)(t0 * 64 + kk) * 2304 + 768 + h * 64 + d];
        }
        __syncthreads();
#pragma unroll
        for (int s = 0; s < 2; ++s) {
            int k = l * 2 + s;
            float4 a4 = {0, 0, 0, 0};
#pragma unroll
            for (int d4 = 0; d4 < 16; ++d4) {
                float4 qa = *(const float4*)&sq[q][d4 * 4];
                float4 ka = *(const float4*)&kt[k][d4 * 4];
                a4.x = fmaf(qa.x, ka.x, a4.x);
                a4.y = fmaf(qa.y, ka.y, a4.y);
                a4.z = fmaf(qa.z, ka.z, a4.z);
                a4.w = fmaf(qa.w, ka.w, a4.w);
            }
            sc[q][t0 * 64 + k] = (a4.x + a4.y + a4.z + a4.w) * 0.125f;
        }
    }
    __syncthreads();
    // phase 2: softmax (store unnormalized exp, keep row sums)
    float pm = -INFINITY;
    for (int s = 0; s < 32; ++s) pm = fmaxf(pm, sc[q][l + 32 * s]);
    redm[q][l] = pm;
    __syncthreads();
    if (l == 0) {
        float m = redm[q][0];
        for (int i = 1; i < 32; ++i) m = fmaxf(m, redm[q][i]);
        rmax[q] = m;
    }
    __syncthreads();
    float m = rmax[q];
    float ps = 0.0f;
    for (int s = 0; s < 32; ++s) {
        int k = l + 32 * s;
        float e = __expf(sc[q][k] - m);
        sc[q][k] = e;
        ps += e;
    }
    __syncthreads();
    redm[q][l] = ps;
    __syncthreads();
    if (l == 0) {
        float s = 0.0f;
        for (int i = 0; i < 32; ++i) s += redm[q][i];
        rsum[q] = s;
    }
    __syncthreads();
    float inv = 1.0f / rsum[q];
    // phase 3: out = attn @ V
    float acc0 = 0.0f, acc1 = 0.0f;
    int d0 = l * 2;
    for (int t0 = 0; t0 < 16; ++t0) {
        __syncthreads();
        for (int idx = tid; idx < 64 * 64; idx += 256) {
            int kk = idx >> 6, d = idx & 63;
            kt[kk][d] = qkv[base + (size_t)(t0 * 64 + kk) * 2304 + 1536 + h * 64 + d];
        }
        __syncthreads();
#pragma unroll
        for (int k = 0; k < 64; ++k) {
            float p = sc[q][t0 * 64 + k];
            acc0 = fmaf(p, kt[k][d0], acc0);
            acc1 = fmaf(p, kt[k][d0 + 1], acc1);
        }
    }
    int token = n0 + q;
    int dt = dtok[b * NTOK + token];
    int j0 = h * 64 + d0;
    float2 o;
    o.x = (j0 < dt) ? acc0 * inv : 0.0f;
    o.y = (j0 + 1 < dt) ? acc1 * inv : 0.0f;
    *(float2*)&attnout[((size_t)b * NTOK + token) * 768 + j0] = o;
}

extern "C" void kernel_launch(void* const* d_in, const int* in_sizes, int n_in,
                              void* d_out, int out_size, void* d_ws, size_t ws_size,
                              hipStream_t stream) {
    const float* x = (const float*)d_in[0];
    const float* ln1g = (const float*)d_in[1];
    const float* ln1b = (const float*)d_in[2];
    const float* rw = (const float*)d_in[3];
    const float* rb = (const float*)d_in[4];
    const float* wqkv = (const float*)d_in[5];
    const float* bqkv = (const float*)d_in[6];
    const float* wo = (const float*)d_in[7];
    const float* bo = (const float*)d_in[8];
    const float* ln2g = (const float*)d_in[9];
    const float* ln2b = (const float*)d_in[10];
    const float* w1 = (const float*)d_in[11];
    const float* b1 = (const float*)d_in[12];
    const float* w2 = (const float*)d_in[13];
    const float* b2 = (const float*)d_in[14];
    float* out = (float*)d_out;

    char* ws = (char*)d_ws;
    size_t off = 0;
    auto alloc = [&](size_t bytes) {
        void* p = ws + off;
        off = (off + bytes + 255) & ~(size_t)255;
        return p;
    };
    float* h1m = (float*)alloc(sizeof(float) * TOKENS * DIM);
    float* probs = (float*)alloc(sizeof(float) * TOKENS * 4);
    float* rprobs = (float*)alloc(sizeof(float) * TOKENS);
    int* assigned = (int*)alloc(sizeof(int) * TOKENS);
    int* dtok = (int*)alloc(sizeof(int) * TOKENS);
    float* qkv = (float*)alloc(sizeof(float) * TOKENS * 3 * DIM);
    float* attno = (float*)alloc(sizeof(float) * TOKENS * DIM);
    float* z = (float*)alloc(sizeof(float) * TOKENS * DIM);
    float* h2 = (float*)alloc(sizeof(float) * TOKENS * DIM);
    float* ffn1 = (float*)alloc(sizeof(float) * TOKENS * 4 * DIM);

    router_kernel<<<TOKENS, 256, 0, stream>>>(x, rw, rb, probs);
    route_kernel<<<BATCH, 1024, 0, stream>>>(probs, assigned, dtok, rprobs);
    ln_mask_kernel<<<TOKENS, 256, 0, stream>>>(x, ln1g, ln1b, dtok, h1m);
    gemm_kernel<0><<<dim3(36, 64), 256, 0, stream>>>(h1m, wqkv, bqkv, qkv, TOKENS, 2304, 768,
                                                     dtok, nullptr, nullptr);
    attn_kernel<<<dim3(128, 12, 4), 256, 0, stream>>>(qkv, dtok, attno);
    gemm_kernel<1><<<dim3(12, 64), 256, 0, stream>>>(attno, wo, bo, z, TOKENS, 768, 768,
                                                     dtok, x, nullptr);
    ln_mask_kernel<<<TOKENS, 256, 0, stream>>>(z, ln2g, ln2b, nullptr, h2);
    gemm_kernel<2><<<dim3(48, 64), 256, 0, stream>>>(h2, w1, b1, ffn1, TOKENS, 3072, 768,
                                                     nullptr, nullptr, nullptr);
    gemm_kernel<3><<<dim3(12, 64), 256, 0, stream>>>(ffn1, w2, b2, out, TOKENS, 768, 3072,
                                                     nullptr, z, rprobs);
}

// Round 2
// 424.031 us; speedup vs baseline: 3.9364x; 3.9364x over previous
//
#include <hip/hip_runtime.h>
#include <math.h>

#define DIM 768
#define NTOK 1024
#define BATCH 4
#define HEADS 12
#define TOKENS (BATCH * NTOK)

typedef __bf16 bf16;
typedef __attribute__((ext_vector_type(8))) __bf16 bf16x8;
typedef __attribute__((ext_vector_type(4))) float floatx4;

// ---------------- router: logits + softmax (double accumulation, exact routing) ----------------
__global__ void router_kernel(const float* __restrict__ x,
                              const float* __restrict__ rw,
                              const float* __restrict__ rb,
                              float* __restrict__ probs) {
    int t = blockIdx.x;
    int tid = threadIdx.x;
    const float* xr = x + (size_t)t * DIM;
    double acc[4] = {0, 0, 0, 0};
    for (int k = tid; k < DIM; k += 256) {
        double xv = (double)xr[k];
        acc[0] += xv * (double)rw[k * 4 + 0];
        acc[1] += xv * (double)rw[k * 4 + 1];
        acc[2] += xv * (double)rw[k * 4 + 2];
        acc[3] += xv * (double)rw[k * 4 + 3];
    }
    __shared__ double red[256];
    __shared__ double logits[4];
    for (int e = 0; e < 4; ++e) {
        red[tid] = acc[e];
        __syncthreads();
        for (int s = 128; s > 0; s >>= 1) {
            if (tid < s) red[tid] += red[tid + s];
            __syncthreads();
        }
        if (tid == 0) logits[e] = red[0] + (double)rb[e];
        __syncthreads();
    }
    if (tid == 0) {
        double m = logits[0];
        for (int e = 1; e < 4; ++e) m = fmax(m, logits[e]);
        double s = 0.0, p[4];
        for (int e = 0; e < 4; ++e) { p[e] = exp(logits[e] - m); s += p[e]; }
        for (int e = 0; e < 4; ++e) probs[(size_t)t * 4 + e] = (float)(p[e] / s);
    }
}

// ---------------- greedy capacity routing: bitonic sort per expert ----------------
__global__ __launch_bounds__(1024) void route_kernel(const float* __restrict__ probs,
                                                     int* __restrict__ dtok_g,
                                                     float* __restrict__ rprobs_g) {
    int b = blockIdx.x;
    int tid = threadIdx.x;
    __shared__ float sp[1024];
    __shared__ int si[1024];
    __shared__ int s_av[1024];
    __shared__ int s_as[1024];
    s_av[tid] = 1;
    s_as[tid] = 0;
    const int ks_e[4] = {409, 307, 204, 104};
    const float* pb = probs + (size_t)b * NTOK * 4;
    for (int e = 3; e >= 1; --e) {
        __syncthreads();
        sp[tid] = s_av[tid] ? pb[tid * 4 + e] : -INFINITY;
        si[tid] = tid;
        for (int size = 2; size <= 1024; size <<= 1) {
            for (int stride = size >> 1; stride > 0; stride >>= 1) {
                __syncthreads();
                int i = tid, j = i ^ stride;
                if (j > i) {
                    float pi = sp[i], pj = sp[j];
                    int ii = si[i], ij = si[j];
                    bool up = ((i & size) == 0);
                    bool before = (pi > pj) || (pi == pj && ii < ij);
                    if (up != before) { sp[i] = pj; sp[j] = pi; si[i] = ij; si[j] = ii; }
                }
            }
        }
        __syncthreads();
        if (tid < ks_e[e]) {
            int tok = si[tid];
            s_as[tok] = e;
            s_av[tok] = 0;
        }
    }
    __syncthreads();
    int a = s_as[tid];
    dtok_g[b * NTOK + tid] = DIM >> (3 - a);
    rprobs_g[b * NTOK + tid] = pb[tid * 4 + a];
}

// ---------------- layernorm fp32 -> bf16 (+ optional feature mask) ----------------
__global__ void ln_mask_kernel(const float* __restrict__ x,
                               const float* __restrict__ g,
                               const float* __restrict__ bta,
                               const int* __restrict__ dtok,  // null -> no mask
                               bf16* __restrict__ out) {
    int t = blockIdx.x;
    int tid = threadIdx.x;
    const float* xr = x + (size_t)t * DIM;
    float s = 0.0f;
    for (int k = tid; k < DIM; k += 256) s += xr[k];
    __shared__ float red[256];
    red[tid] = s;
    __syncthreads();
    for (int st = 128; st > 0; st >>= 1) {
        if (tid < st) red[tid] += red[tid + st];
        __syncthreads();
    }
    float mu = red[0] / DIM;
    __syncthreads();
    float v = 0.0f;
    for (int k = tid; k < DIM; k += 256) { float d = xr[k] - mu; v += d * d; }
    red[tid] = v;
    __syncthreads();
    for (int st = 128; st > 0; st >>= 1) {
        if (tid < st) red[tid] += red[tid + st];
        __syncthreads();
    }
    float rs = rsqrtf(red[0] / DIM + 1e-5f);
    int d = dtok ? dtok[t] : DIM;
    for (int k = tid; k < DIM; k += 256) {
        float val = (xr[k] - mu) * rs * g[k] + bta[k];
        out[(size_t)t * DIM + k] = (bf16)((k < d) ? val : 0.0f);
    }
}

// ---------------- transpose + convert W[K][N] fp32 -> Wt[N][K] bf16 ----------------
__global__ __launch_bounds__(256) void transpose_bf16_kernel(const float* __restrict__ W,
                                                             bf16* __restrict__ Wt,
                                                             int K, int N) {
    __shared__ float t[32][33];
    int bx = blockIdx.x * 32;  // n
    int by = blockIdx.y * 32;  // k
    int tx = threadIdx.x, ty = threadIdx.y;  // (32, 8)
#pragma unroll
    for (int i = 0; i < 4; ++i)
        t[ty + i * 8][tx] = W[(size_t)(by + ty + i * 8) * N + bx + tx];
    __syncthreads();
#pragma unroll
    for (int i = 0; i < 4; ++i)
        Wt[(size_t)(bx + ty + i * 8) * K + by + tx] = (bf16)t[tx][ty + i * 8];
}

// ---------------- bf16 MFMA GEMM, 128x128 tile, BK=32, fused epilogues ----------------
// A[M][K] bf16 row-major, Bt[N][K] bf16 row-major (pre-transposed weight).
// MODE 0: QKV — +bias, mask (col%768 < dtok[row]) -> bf16
// MODE 1: WO  — +bias, mask (col < dtok[row]) + aux(x) -> fp32
// MODE 2: FFN1 — +bias, exact GELU -> bf16
// MODE 3: FFN2 — +bias, out = aux(z) + rp[row]*c -> fp32
#define LDT 40  // padded LDS row (bf16 units): 80 B stride -> 2-way conflicts only, 16B aligned
template <int MODE>
__global__ __launch_bounds__(256) void gemm_mfma(const bf16* __restrict__ A,
                                                 const bf16* __restrict__ Bt,
                                                 const float* __restrict__ bias,
                                                 void* __restrict__ Cout,
                                                 int M, int NN, int K,
                                                 const int* __restrict__ dtok,
                                                 const float* __restrict__ aux,
                                                 const float* __restrict__ rp) {
    __shared__ bf16 As[128 * LDT];
    __shared__ bf16 Bs[128 * LDT];
    int n0 = blockIdx.x * 128;
    int m0 = blockIdx.y * 128;
    int tid = threadIdx.x;
    int wv = tid >> 6;
    int lane = tid & 63;
    int l16 = lane & 15, q4 = lane >> 4;
    int wm = (wv >> 1) * 64, wn = (wv & 1) * 64;
    floatx4 acc[4][4] = {};
    for (int k0 = 0; k0 < K; k0 += 32) {
        __syncthreads();
#pragma unroll
        for (int s = tid; s < 512; s += 256) {
            int row = s >> 2, part = s & 3;
            *(floatx4*)&As[row * LDT + part * 8] =
                *(const floatx4*)&A[(size_t)(m0 + row) * K + k0 + part * 8];
            *(floatx4*)&Bs[row * LDT + part * 8] =
                *(const floatx4*)&Bt[(size_t)(n0 + row) * K + k0 + part * 8];
        }
        __syncthreads();
        bf16x8 af[4], bfr[4];
#pragma unroll
        for (int t = 0; t < 4; ++t) {
            af[t] = *(const bf16x8*)&As[(wm + t * 16 + l16) * LDT + q4 * 8];
            bfr[t] = *(const bf16x8*)&Bs[(wn + t * 16 + l16) * LDT + q4 * 8];
        }
#pragma unroll
        for (int i = 0; i < 4; ++i)
#pragma unroll
            for (int j = 0; j < 4; ++j)
                acc[i][j] = __builtin_amdgcn_mfma_f32_16x16x32_bf16(af[i], bfr[j], acc[i][j], 0, 0, 0);
    }
    // epilogue: C layout col = l16, row = q4*4 + reg
#pragma unroll
    for (int i = 0; i < 4; ++i) {
#pragma unroll
        for (int j = 0; j < 4; ++j) {
            int col = n0 + wn + j * 16 + l16;
#pragma unroll
            for (int r = 0; r < 4; ++r) {
                int row = m0 + wm + i * 16 + q4 * 4 + r;
                float c = acc[i][j][r] + bias[col];
                if (MODE == 0) {
                    int jm = col % 768;
                    c = (jm < dtok[row]) ? c : 0.0f;
                    ((bf16*)Cout)[(size_t)row * NN + col] = (bf16)c;
                } else if (MODE == 1) {
                    c = (col < dtok[row]) ? c : 0.0f;
                    c += aux[(size_t)row * NN + col];
                    ((float*)Cout)[(size_t)row * NN + col] = c;
                } else if (MODE == 2) {
                    c = 0.5f * c * (1.0f + erff(c * 0.70710678118654752f));
                    ((bf16*)Cout)[(size_t)row * NN + col] = (bf16)c;
                } else {
                    c = aux[(size_t)row * NN + col] + rp[row] * c;
                    ((float*)Cout)[(size_t)row * NN + col] = c;
                }
            }
        }
    }
}

// ---------------- attention: bf16 MFMA, flash-style online softmax ----------------
// block: 64 Q rows (4 waves x 16), one (b,h); loop over 16 K-tiles of 64 keys.
#define LDH 72  // padded row (bf16 units) for 64-wide tiles: 144 B stride
__global__ __launch_bounds__(256) void attn_mfma(const bf16* __restrict__ qkv,
                                                 const int* __restrict__ dtok,
                                                 bf16* __restrict__ attno) {
    int qt = blockIdx.x;  // 0..15
    int h = blockIdx.y;   // 0..11
    int b = blockIdx.z;   // 0..3
    int tid = threadIdx.x;
    int wv = tid >> 6;
    int lane = tid & 63;
    int l16 = lane & 15, q4 = lane >> 4;
    __shared__ bf16 Qs[64 * LDH];
    __shared__ bf16 Ks[64 * LDH];
    __shared__ bf16 Vt[64 * LDH];
    __shared__ bf16 Ps[4][16 * LDH];
    size_t base = (size_t)b * NTOK * 2304;
    // stage Q tile (64 rows x 64 dims)
    for (int s = tid; s < 512; s += 256) {
        int row = s >> 3, part = s & 7;
        *(floatx4*)&Qs[row * LDH + part * 8] =
            *(const floatx4*)&qkv[base + (size_t)(qt * 64 + row) * 2304 + h * 64 + part * 8];
    }
    floatx4 o[4] = {};
    float m_r[4] = {-INFINITY, -INFINITY, -INFINITY, -INFINITY};
    float l_r[4] = {0.0f, 0.0f, 0.0f, 0.0f};
    for (int kt = 0; kt < 16; ++kt) {
        __syncthreads();
        // stage K tile and V tile (transposed)
        for (int s = tid; s < 512; s += 256) {
            int row = s >> 3, part = s & 7;
            *(floatx4*)&Ks[row * LDH + part * 8] =
                *(const floatx4*)&qkv[base + (size_t)(kt * 64 + row) * 2304 + 768 + h * 64 + part * 8];
            floatx4 vv =
                *(const floatx4*)&qkv[base + (size_t)(kt * 64 + row) * 2304 + 1536 + h * 64 + part * 8];
            const bf16* vp = (const bf16*)&vv;
#pragma unroll
            for (int j = 0; j < 8; ++j) Vt[(part * 8 + j) * LDH + row] = vp[j];
        }
        __syncthreads();
        // S = Q K^T / 8 (wave's 16 Q rows x 64 keys)
        floatx4 sc[4] = {};
#pragma unroll
        for (int ch = 0; ch < 2; ++ch) {
            bf16x8 aq = *(const bf16x8*)&Qs[(wv * 16 + l16) * LDH + ch * 32 + q4 * 8];
#pragma unroll
            for (int nt = 0; nt < 4; ++nt) {
                bf16x8 bk = *(const bf16x8*)&Ks[(nt * 16 + l16) * LDH + ch * 32 + q4 * 8];
                sc[nt] = __builtin_amdgcn_mfma_f32_16x16x32_bf16(aq, bk, sc[nt], 0, 0, 0);
            }
        }
        // online softmax over the 64 new columns
        float alpha[4], psum[4];
#pragma unroll
        for (int r = 0; r < 4; ++r) {
            float v0 = fmaxf(fmaxf(sc[0][r], sc[1][r]), fmaxf(sc[2][r], sc[3][r])) * 0.125f;
#pragma unroll
            for (int msk = 1; msk < 16; msk <<= 1) v0 = fmaxf(v0, __shfl_xor(v0, msk));
            float mn = fmaxf(m_r[r], v0);
            alpha[r] = __expf(m_r[r] - mn);
            m_r[r] = mn;
            psum[r] = 0.0f;
        }
#pragma unroll
        for (int nt = 0; nt < 4; ++nt)
#pragma unroll
            for (int r = 0; r < 4; ++r) {
                float p = __expf(sc[nt][r] * 0.125f - m_r[r]);
                psum[r] += p;
                Ps[wv][(q4 * 4 + r) * LDH + nt * 16 + l16] = (bf16)p;
            }
#pragma unroll
        for (int r = 0; r < 4; ++r) {
            float s = psum[r];
#pragma unroll
            for (int msk = 1; msk < 16; msk <<= 1) s += __shfl_xor(s, msk);
            l_r[r] = l_r[r] * alpha[r] + s;
        }
#pragma unroll
        for (int dt = 0; dt < 4; ++dt)
#pragma unroll
            for (int r = 0; r < 4; ++r) o[dt][r] *= alpha[r];
        __syncthreads();  // P writes -> P reads (uniform across block)
        // O += P V
#pragma unroll
        for (int ch = 0; ch < 2; ++ch) {
            bf16x8 ap = *(const bf16x8*)&Ps[wv][l16 * LDH + ch * 32 + q4 * 8];
#pragma unroll
            for (int dt = 0; dt < 4; ++dt) {
                bf16x8 bv = *(const bf16x8*)&Vt[(dt * 16 + l16) * LDH + ch * 32 + q4 * 8];
                o[dt] = __builtin_amdgcn_mfma_f32_16x16x32_bf16(ap, bv, o[dt], 0, 0, 0);
            }
        }
    }
    // normalize, mask, store bf16
#pragma unroll
    for (int r = 0; r < 4; ++r) {
        int tokrow = qt * 64 + wv * 16 + q4 * 4 + r;
        int dt_tok = dtok[b * NTOK + tokrow];
        float inv = 1.0f / l_r[r];
#pragma unroll
        for (int dt = 0; dt < 4; ++dt) {
            int col = h * 64 + dt * 16 + l16;
            float val = (col < dt_tok) ? o[dt][r] * inv : 0.0f;
            attno[((size_t)b * NTOK + tokrow) * DIM + col] = (bf16)val;
        }
    }
}

extern "C" void kernel_launch(void* const* d_in, const int* in_sizes, int n_in,
                              void* d_out, int out_size, void* d_ws, size_t ws_size,
                              hipStream_t stream) {
    const float* x = (const float*)d_in[0];
    const float* ln1g = (const float*)d_in[1];
    const float* ln1b = (const float*)d_in[2];
    const float* rw = (const float*)d_in[3];
    const float* rb = (const float*)d_in[4];
    const float* wqkv = (const float*)d_in[5];
    const float* bqkv = (const float*)d_in[6];
    const float* wo = (const float*)d_in[7];
    const float* bo = (const float*)d_in[8];
    const float* ln2g = (const float*)d_in[9];
    const float* ln2b = (const float*)d_in[10];
    const float* w1 = (const float*)d_in[11];
    const float* b1 = (const float*)d_in[12];
    const float* w2 = (const float*)d_in[13];
    const float* b2 = (const float*)d_in[14];
    float* out = (float*)d_out;

    char* ws = (char*)d_ws;
    size_t off = 0;
    auto alloc = [&](size_t bytes) {
        void* p = ws + off;
        off = (off + bytes + 255) & ~(size_t)255;
        return p;
    };
    bf16* h1m = (bf16*)alloc(sizeof(bf16) * TOKENS * DIM);
    float* probs = (float*)alloc(sizeof(float) * TOKENS * 4);
    float* rprobs = (float*)alloc(sizeof(float) * TOKENS);
    int* dtok = (int*)alloc(sizeof(int) * TOKENS);
    bf16* qkvb = (bf16*)alloc(sizeof(bf16) * TOKENS * 3 * DIM);
    bf16* attno = (bf16*)alloc(sizeof(bf16) * TOKENS * DIM);
    float* z = (float*)alloc(sizeof(float) * TOKENS * DIM);
    bf16* h2 = (bf16*)alloc(sizeof(bf16) * TOKENS * DIM);
    bf16* ffn1 = (bf16*)alloc(sizeof(bf16) * TOKENS * 4 * DIM);
    bf16* wqkvT = (bf16*)alloc(sizeof(bf16) * DIM * 3 * DIM);
    bf16* woT = (bf16*)alloc(sizeof(bf16) * DIM * DIM);
    bf16* w1T = (bf16*)alloc(sizeof(bf16) * DIM * 4 * DIM);
    bf16* w2T = (bf16*)alloc(sizeof(bf16) * 4 * DIM * DIM);

    dim3 tb(32, 8);
    transpose_bf16_kernel<<<dim3(2304 / 32, 768 / 32), tb, 0, stream>>>(wqkv, wqkvT, 768, 2304);
    transpose_bf16_kernel<<<dim3(768 / 32, 768 / 32), tb, 0, stream>>>(wo, woT, 768, 768);
    transpose_bf16_kernel<<<dim3(3072 / 32, 768 / 32), tb, 0, stream>>>(w1, w1T, 768, 3072);
    transpose_bf16_kernel<<<dim3(768 / 32, 3072 / 32), tb, 0, stream>>>(w2, w2T, 3072, 768);

    router_kernel<<<TOKENS, 256, 0, stream>>>(x, rw, rb, probs);
    route_kernel<<<BATCH, 1024, 0, stream>>>(probs, dtok, rprobs);
    ln_mask_kernel<<<TOKENS, 256, 0, stream>>>(x, ln1g, ln1b, dtok, h1m);
    gemm_mfma<0><<<dim3(2304 / 128, 4096 / 128), 256, 0, stream>>>(
        h1m, wqkvT, bqkv, qkvb, TOKENS, 2304, 768, dtok, nullptr, nullptr);
    attn_mfma<<<dim3(16, 12, 4), 256, 0, stream>>>(qkvb, dtok, attno);
    gemm_mfma<1><<<dim3(768 / 128, 4096 / 128), 256, 0, stream>>>(
        attno, woT, bo, z, TOKENS, 768, 768, dtok, x, nullptr);
    ln_mask_kernel<<<TOKENS, 256, 0, stream>>>(z, ln2g, ln2b, nullptr, h2);
    gemm_mfma<2><<<dim3(3072 / 128, 4096 / 128), 256, 0, stream>>>(
        h2, w1T, b1, ffn1, TOKENS, 3072, 768, nullptr, nullptr, nullptr);
    gemm_mfma<3><<<dim3(768 / 128, 4096 / 128), 256, 0, stream>>>(
        ffn1, w2T, b2, out, TOKENS, 768, 3072, nullptr, z, rprobs);
}